// Round 1
// baseline (467.763 us; speedup 1.0000x reference)
//
#include <hip/hip_runtime.h>

typedef __bf16 bf16;
typedef __bf16 bf16x8 __attribute__((ext_vector_type(8)));
typedef __bf16 bf16x4 __attribute__((ext_vector_type(4)));
typedef float f32x4 __attribute__((ext_vector_type(4)));

__device__ __forceinline__ bf16 f2bf(float f) {
    // RNE float->bf16 (inputs are finite; NaN path not needed)
    unsigned u = __builtin_bit_cast(unsigned, f);
    u += 0x7fffu + ((u >> 16) & 1u);
    unsigned short s = (unsigned short)(u >> 16);
    return __builtin_bit_cast(bf16, s);
}

__device__ __forceinline__ f32x4 mfma16(bf16x8 a, bf16x8 b, f32x4 c) {
    return __builtin_amdgcn_mfma_f32_16x16x32_bf16(a, b, c, 0, 0, 0);
}

// ---------------------------------------------------------------------------
// Cast the four 1024x1024 fp32 weights to bf16, packed contiguously in ws.
// ---------------------------------------------------------------------------
__global__ __launch_bounds__(256) void cast_weights(
    const float* __restrict__ w0, const float* __restrict__ w1,
    const float* __restrict__ w2, const float* __restrict__ w3,
    bf16* __restrict__ dst) {
    long i4 = (long)blockIdx.x * 256 + threadIdx.x;   // float4 index, 4*262144 total
    int which = (int)(i4 >> 18);                      // 262144 float4 per weight
    long loc = (i4 & 262143) << 2;                    // element offset
    const float* src = which == 0 ? w0 : which == 1 ? w1 : which == 2 ? w2 : w3;
    float4 f = *(const float4*)(src + loc);
    bf16x4 o;
    o[0] = f2bf(f.x); o[1] = f2bf(f.y); o[2] = f2bf(f.z); o[3] = f2bf(f.w);
    *(bf16x4*)(dst + ((long)which << 20) + loc) = o;
}

// ---------------------------------------------------------------------------
// C[M,N] = A[M,K] @ W[N,K]^T + bias   (torch Linear form)
// M=8192, N=K=1024. 128x128 block tile, BK=32, 4 waves each 64x64.
// AT = float (convert to bf16 during staging) or bf16. OT = bf16 or float.
// ---------------------------------------------------------------------------
template <typename AT, typename OT>
__global__ __launch_bounds__(256) void gemm_bt(
    const AT* __restrict__ A, const bf16* __restrict__ Wt,
    const float* __restrict__ bias, OT* __restrict__ Y) {
    constexpr int Kd = 1024, Nd = 1024;
    __shared__ bf16 As[128 * 32];
    __shared__ bf16 Bs[128 * 32];
    const int tid = threadIdx.x;
    const int wid = tid >> 6, lane = tid & 63;
    const int l16 = lane & 15, quad = lane >> 4;
    const int n0 = blockIdx.x * 128, m0 = blockIdx.y * 128;
    const int mh = (wid >> 1) * 64, nh = (wid & 1) * 64;

    f32x4 acc[4][4];
#pragma unroll
    for (int i = 0; i < 4; ++i)
#pragma unroll
        for (int j = 0; j < 4; ++j) acc[i][j] = (f32x4){0.f, 0.f, 0.f, 0.f};

    const int sr = tid >> 1;         // staging row 0..127
    const int sc = (tid & 1) * 16;   // staging col (16 elements per thread)

    for (int k0 = 0; k0 < Kd; k0 += 32) {
        if constexpr (sizeof(AT) == 4) {
            const float* ap = (const float*)A + (long)(m0 + sr) * Kd + k0 + sc;
            float4 f0 = *(const float4*)(ap + 0);
            float4 f1 = *(const float4*)(ap + 4);
            float4 f2 = *(const float4*)(ap + 8);
            float4 f3 = *(const float4*)(ap + 12);
            bf16x8 p0, p1;
            p0[0] = f2bf(f0.x); p0[1] = f2bf(f0.y); p0[2] = f2bf(f0.z); p0[3] = f2bf(f0.w);
            p0[4] = f2bf(f1.x); p0[5] = f2bf(f1.y); p0[6] = f2bf(f1.z); p0[7] = f2bf(f1.w);
            p1[0] = f2bf(f2.x); p1[1] = f2bf(f2.y); p1[2] = f2bf(f2.z); p1[3] = f2bf(f2.w);
            p1[4] = f2bf(f3.x); p1[5] = f2bf(f3.y); p1[6] = f2bf(f3.z); p1[7] = f2bf(f3.w);
            *(bf16x8*)&As[sr * 32 + sc] = p0;
            *(bf16x8*)&As[sr * 32 + sc + 8] = p1;
        } else {
            const bf16* ap = (const bf16*)A + (long)(m0 + sr) * Kd + k0 + sc;
            *(bf16x8*)&As[sr * 32 + sc] = *(const bf16x8*)ap;
            *(bf16x8*)&As[sr * 32 + sc + 8] = *(const bf16x8*)(ap + 8);
        }
        {
            const bf16* bp = Wt + (long)(n0 + sr) * Kd + k0 + sc;
            *(bf16x8*)&Bs[sr * 32 + sc] = *(const bf16x8*)bp;
            *(bf16x8*)&Bs[sr * 32 + sc + 8] = *(const bf16x8*)(bp + 8);
        }
        __syncthreads();
        bf16x8 af[4], bq[4];
#pragma unroll
        for (int i = 0; i < 4; ++i)
            af[i] = *(const bf16x8*)&As[(mh + i * 16 + l16) * 32 + quad * 8];
#pragma unroll
        for (int i = 0; i < 4; ++i)
            bq[i] = *(const bf16x8*)&Bs[(nh + i * 16 + l16) * 32 + quad * 8];
#pragma unroll
        for (int i = 0; i < 4; ++i)
#pragma unroll
            for (int j = 0; j < 4; ++j)
                acc[i][j] = mfma16(af[i], bq[j], acc[i][j]);
        __syncthreads();
    }

#pragma unroll
    for (int j = 0; j < 4; ++j) {
        int col = n0 + nh + j * 16 + l16;
        float bv = bias[col];
#pragma unroll
        for (int i = 0; i < 4; ++i) {
#pragma unroll
            for (int r = 0; r < 4; ++r) {
                int row = m0 + mh + i * 16 + quad * 4 + r;
                float v = acc[i][j][r] + bv;
                if constexpr (sizeof(OT) == 4)
                    ((float*)Y)[(long)row * Nd + col] = v;
                else
                    ((bf16*)Y)[(long)row * Nd + col] = f2bf(v);
            }
        }
    }
}

// ---------------------------------------------------------------------------
// StableMax cross-attention. One block per (b, h, 128-row q-tile).
// 4 waves, each owns 32 q rows. Q frags in registers; KV tiles of 64.
// No online-max needed: s(x) accumulates linearly -> plain num/den sums.
// ---------------------------------------------------------------------------
__global__ __launch_bounds__(256) void attn_kernel(
    const bf16* __restrict__ Q, const bf16* __restrict__ K,
    const bf16* __restrict__ V, bf16* __restrict__ C) {
    constexpr int E = 1024, S = 2048, HD = 64;
    __shared__ bf16 Ks[64 * 72];       // [kv][d], stride 72 (pad vs 1-bank stride)
    __shared__ bf16 VTs[64 * 72];      // [d][kv] transposed
    __shared__ bf16 Ps[4][32 * 72];    // per-wave P tile [q_local][kv]

    const int tid = threadIdx.x;
    const int wid = tid >> 6, lane = tid & 63;
    const int l16 = lane & 15, quad = lane >> 4;
    const int qt = blockIdx.x, h = blockIdx.y, b = blockIdx.z;

    const long q0 = (long)b * S + qt * 128;
    const bf16* Qg = Q + q0 * E + h * HD;
    const bf16* Kg = K + (long)b * S * E + h * HD;
    const bf16* Vg = V + (long)b * S * E + h * HD;

    // Q fragments for this wave's 32 rows: [mt][kc], A-layout (m=l16, k=quad*8+j)
    bf16x8 qf[2][2];
#pragma unroll
    for (int mt = 0; mt < 2; ++mt)
#pragma unroll
        for (int kc = 0; kc < 2; ++kc)
            qf[mt][kc] = *(const bf16x8*)(Qg + (long)(wid * 32 + mt * 16 + l16) * E + kc * 32 + quad * 8);

    f32x4 ctx[2][4];
    f32x4 den[2];
#pragma unroll
    for (int mt = 0; mt < 2; ++mt) {
        den[mt] = (f32x4){0.f, 0.f, 0.f, 0.f};
#pragma unroll
        for (int nt = 0; nt < 4; ++nt) ctx[mt][nt] = (f32x4){0.f, 0.f, 0.f, 0.f};
    }

    const int krow = tid >> 2, kcol = (tid & 3) * 16;  // K staging
    const int vkv = tid & 63, vdh = (tid >> 6) * 16;   // V staging (transpose)

    for (int kv0 = 0; kv0 < S; kv0 += 64) {
        {   // stage K tile [64][64] row-major
            const bf16* kp = Kg + (long)(kv0 + krow) * E + kcol;
            *(bf16x8*)&Ks[krow * 72 + kcol] = *(const bf16x8*)kp;
            *(bf16x8*)&Ks[krow * 72 + kcol + 8] = *(const bf16x8*)(kp + 8);
        }
        {   // stage V tile transposed -> VTs[d][kv]
            const bf16* vp = Vg + (long)(kv0 + vkv) * E + vdh;
            bf16x8 v0 = *(const bf16x8*)vp;
            bf16x8 v1 = *(const bf16x8*)(vp + 8);
#pragma unroll
            for (int j = 0; j < 8; ++j) VTs[(vdh + j) * 72 + vkv] = v0[j];
#pragma unroll
            for (int j = 0; j < 8; ++j) VTs[(vdh + 8 + j) * 72 + vkv] = v1[j];
        }
        __syncthreads();

        // S = Q K^T / 8 -> stablemax s-values
        bf16x8 kf[4][2];
#pragma unroll
        for (int nt = 0; nt < 4; ++nt)
#pragma unroll
            for (int kc = 0; kc < 2; ++kc)
                kf[nt][kc] = *(const bf16x8*)&Ks[(nt * 16 + l16) * 72 + kc * 32 + quad * 8];
        f32x4 sacc[2][4];
#pragma unroll
        for (int mt = 0; mt < 2; ++mt)
#pragma unroll
            for (int nt = 0; nt < 4; ++nt) sacc[mt][nt] = (f32x4){0.f, 0.f, 0.f, 0.f};
#pragma unroll
        for (int mt = 0; mt < 2; ++mt)
#pragma unroll
            for (int nt = 0; nt < 4; ++nt)
#pragma unroll
                for (int kc = 0; kc < 2; ++kc)
                    sacc[mt][nt] = mfma16(qf[mt][kc], kf[nt][kc], sacc[mt][nt]);

        // stablemax: s = x>=0 ? x+1 : 1/(1-x); accumulate den; write P (bf16) to LDS
#pragma unroll
        for (int mt = 0; mt < 2; ++mt) {
#pragma unroll
            for (int nt = 0; nt < 4; ++nt) {
                f32x4 s;
#pragma unroll
                for (int r = 0; r < 4; ++r) {
                    float x = sacc[mt][nt][r] * 0.125f;
                    float sv = (x >= 0.f) ? (x + 1.f) : __builtin_amdgcn_rcpf(1.f - x);
                    s[r] = sv;
                    Ps[wid][(mt * 16 + quad * 4 + r) * 72 + nt * 16 + l16] = f2bf(sv);
                }
                den[mt] += s;
            }
        }

        // PV: ctx += P @ V   (A from own Ps region, B from VTs contiguous)
        bf16x8 pf[2][2], vf[4][2];
#pragma unroll
        for (int mt = 0; mt < 2; ++mt)
#pragma unroll
            for (int kc = 0; kc < 2; ++kc)
                pf[mt][kc] = *(const bf16x8*)&Ps[wid][(mt * 16 + l16) * 72 + kc * 32 + quad * 8];
#pragma unroll
        for (int nt = 0; nt < 4; ++nt)
#pragma unroll
            for (int kc = 0; kc < 2; ++kc)
                vf[nt][kc] = *(const bf16x8*)&VTs[(nt * 16 + l16) * 72 + kc * 32 + quad * 8];
#pragma unroll
        for (int mt = 0; mt < 2; ++mt)
#pragma unroll
            for (int nt = 0; nt < 4; ++nt)
#pragma unroll
                for (int kc = 0; kc < 2; ++kc)
                    ctx[mt][nt] = mfma16(pf[mt][kc], vf[nt][kc], ctx[mt][nt]);
        __syncthreads();
    }

    // reduce den across the 16 lanes of each quad (cols are disjoint per lane)
#pragma unroll
    for (int mt = 0; mt < 2; ++mt) {
#pragma unroll
        for (int r = 0; r < 4; ++r) {
            float d = den[mt][r];
            d += __shfl_xor(d, 1, 16);
            d += __shfl_xor(d, 2, 16);
            d += __shfl_xor(d, 4, 16);
            d += __shfl_xor(d, 8, 16);
            den[mt][r] = d;
        }
    }

    // ctx / den -> bf16 context, layout [b*S+q][h*HD+d]
#pragma unroll
    for (int mt = 0; mt < 2; ++mt) {
#pragma unroll
        for (int nt = 0; nt < 4; ++nt) {
#pragma unroll
            for (int r = 0; r < 4; ++r) {
                int row = wid * 32 + mt * 16 + quad * 4 + r;
                float v = ctx[mt][nt][r] * __builtin_amdgcn_rcpf(den[mt][r]);
                C[(q0 + row) * E + h * HD + nt * 16 + l16] = f2bf(v);
            }
        }
    }
}

// ---------------------------------------------------------------------------
extern "C" void kernel_launch(void* const* d_in, const int* in_sizes, int n_in,
                              void* d_out, int out_size, void* d_ws, size_t ws_size,
                              hipStream_t stream) {
    const float* query = (const float*)d_in[0];
    const float* keyv  = (const float*)d_in[1];
    const float* Wq = (const float*)d_in[2];
    const float* bq = (const float*)d_in[3];
    const float* Wk = (const float*)d_in[4];
    const float* bk = (const float*)d_in[5];
    const float* Wv = (const float*)d_in[6];
    const float* bv = (const float*)d_in[7];
    const float* Wo = (const float*)d_in[8];
    const float* bo = (const float*)d_in[9];

    char* ws = (char*)d_ws;
    bf16* Wb = (bf16*)ws;                        // 4 x 1M bf16 = 8 MB (Wq,Wk,Wv,Wo)
    bf16* Qw = (bf16*)(ws + (8l << 20));         // 8192x1024 bf16 = 16 MB
    bf16* Kw = (bf16*)(ws + (24l << 20));
    bf16* Vw = (bf16*)(ws + (40l << 20));
    bf16* Cw = (bf16*)(ws + (56l << 20));        // context, 16 MB (total 72 MB)

    cast_weights<<<4096, 256, 0, stream>>>(Wq, Wk, Wv, Wo, Wb);

    dim3 gg(8, 64);  // N/128, M/128
    gemm_bt<float, bf16><<<gg, 256, 0, stream>>>(query, Wb, bq, Qw);
    gemm_bt<float, bf16><<<gg, 256, 0, stream>>>(keyv, Wb + (1l << 20), bk, Kw);
    gemm_bt<float, bf16><<<gg, 256, 0, stream>>>(keyv, Wb + (2l << 20), bv, Vw);

    attn_kernel<<<dim3(16, 16, 4), 256, 0, stream>>>(Qw, Kw, Vw, Cw);

    gemm_bt<bf16, float><<<gg, 256, 0, stream>>>(Cw, Wb + (3l << 20), bo, (float*)d_out);
}

// Round 2
// 390.233 us; speedup vs baseline: 1.1987x; 1.1987x over previous
//
#include <hip/hip_runtime.h>

typedef __bf16 bf16;
typedef __bf16 bf16x8 __attribute__((ext_vector_type(8)));
typedef __bf16 bf16x4 __attribute__((ext_vector_type(4)));
typedef float f32x4 __attribute__((ext_vector_type(4)));

__device__ __forceinline__ bf16 f2bf(float f) {
    // RNE float->bf16 (finite inputs)
    unsigned u = __builtin_bit_cast(unsigned, f);
    u += 0x7fffu + ((u >> 16) & 1u);
    unsigned short s = (unsigned short)(u >> 16);
    return __builtin_bit_cast(bf16, s);
}

__device__ __forceinline__ f32x4 mfma16(bf16x8 a, bf16x8 b, f32x4 c) {
    return __builtin_amdgcn_mfma_f32_16x16x32_bf16(a, b, c, 0, 0, 0);
}

// async global -> LDS, 16 bytes per lane (dest = wave-uniform base + lane*16)
#define GLOAD_LDS16(gp, lp)                                                    \
    __builtin_amdgcn_global_load_lds(                                          \
        (const __attribute__((address_space(1))) unsigned int*)(gp),           \
        (__attribute__((address_space(3))) unsigned int*)(lp), 16, 0, 0)

// ---------------------------------------------------------------------------
// Cast the four 1024x1024 fp32 weights + key_value (8M floats) to bf16.
// ---------------------------------------------------------------------------
__global__ __launch_bounds__(256) void cast_inputs(
    const float* __restrict__ w0, const float* __restrict__ w1,
    const float* __restrict__ w2, const float* __restrict__ w3,
    const float* __restrict__ kv, bf16* __restrict__ Wb,
    bf16* __restrict__ KVa) {
    long i4 = (long)blockIdx.x * 256 + threadIdx.x;  // float4 index
    const float* src;
    bf16* dst;
    long loc;
    if (i4 < 1048576) {  // 4 weights x 262144 float4
        int which = (int)(i4 >> 18);
        loc = (i4 & 262143) << 2;
        src = which == 0 ? w0 : which == 1 ? w1 : which == 2 ? w2 : w3;
        dst = Wb + ((long)which << 20);
    } else {             // key_value: 2097152 float4
        loc = (i4 - 1048576) << 2;
        src = kv;
        dst = KVa;
    }
    float4 f = *(const float4*)(src + loc);
    bf16x4 o;
    o[0] = f2bf(f.x); o[1] = f2bf(f.y); o[2] = f2bf(f.z); o[3] = f2bf(f.w);
    *(bf16x4*)(dst + loc) = o;
}

// ---------------------------------------------------------------------------
// C[M,N] = A[M,K] @ W[N,K]^T + bias. M=8192, N=K=1024.
// 128x128 tile, BK=32, 4 waves each 64x64 (m97 pattern).
// AT: float (convert during staging) or bf16 (global_load_lds).
// OM: 0 = bf16 row-major, 1 = f32 row-major, 2 = bf16 V^T scatter [b,h,d,skv]
// ---------------------------------------------------------------------------
template <typename AT, int OM>
__global__ __launch_bounds__(256) void gemm_bt(
    const AT* __restrict__ A, const bf16* __restrict__ Wt,
    const float* __restrict__ bias, void* __restrict__ Yv) {
    constexpr int Kd = 1024, Nd = 1024;
    __shared__ bf16 As[128 * 32];
    __shared__ bf16 Bs[128 * 32];
    const int tid = threadIdx.x;
    const int wid = tid >> 6, lane = tid & 63;
    const int l16 = lane & 15, quad = lane >> 4;
    const int n0 = blockIdx.x * 128, m0 = blockIdx.y * 128;
    const int mh = (wid >> 1) * 64, nh = (wid & 1) * 64;

    f32x4 acc[4][4];
#pragma unroll
    for (int i = 0; i < 4; ++i)
#pragma unroll
        for (int j = 0; j < 4; ++j) acc[i][j] = (f32x4){0.f, 0.f, 0.f, 0.f};

    // chunk ids for global_load_lds staging (each chunk = 16B = 8 bf16)
    const int c0 = tid, c1 = tid + 256;
    // fp32-A register staging coords
    const int sr = tid >> 1, sc = (tid & 1) * 16;

    for (int k0 = 0; k0 < Kd; k0 += 32) {
        // ---- B tile via async global->LDS
        GLOAD_LDS16(Wt + (long)(n0 + (c0 >> 2)) * Kd + k0 + (c0 & 3) * 8, &Bs[c0 * 8]);
        GLOAD_LDS16(Wt + (long)(n0 + (c1 >> 2)) * Kd + k0 + (c1 & 3) * 8, &Bs[(long)c1 * 8]);
        // ---- A tile
        if constexpr (sizeof(AT) == 4) {
            const float* ap = (const float*)A + (long)(m0 + sr) * Kd + k0 + sc;
            float4 f0 = *(const float4*)(ap + 0);
            float4 f1 = *(const float4*)(ap + 4);
            float4 f2 = *(const float4*)(ap + 8);
            float4 f3 = *(const float4*)(ap + 12);
            bf16x8 p0, p1;
            p0[0] = f2bf(f0.x); p0[1] = f2bf(f0.y); p0[2] = f2bf(f0.z); p0[3] = f2bf(f0.w);
            p0[4] = f2bf(f1.x); p0[5] = f2bf(f1.y); p0[6] = f2bf(f1.z); p0[7] = f2bf(f1.w);
            p1[0] = f2bf(f2.x); p1[1] = f2bf(f2.y); p1[2] = f2bf(f2.z); p1[3] = f2bf(f2.w);
            p1[4] = f2bf(f3.x); p1[5] = f2bf(f3.y); p1[6] = f2bf(f3.z); p1[7] = f2bf(f3.w);
            *(bf16x8*)&As[sr * 32 + sc] = p0;
            *(bf16x8*)&As[sr * 32 + sc + 8] = p1;
        } else {
            GLOAD_LDS16((const bf16*)A + (long)(m0 + (c0 >> 2)) * Kd + k0 + (c0 & 3) * 8, &As[c0 * 8]);
            GLOAD_LDS16((const bf16*)A + (long)(m0 + (c1 >> 2)) * Kd + k0 + (c1 & 3) * 8, &As[(long)c1 * 8]);
        }
        __syncthreads();
        bf16x8 af[4], bq[4];
#pragma unroll
        for (int i = 0; i < 4; ++i)
            af[i] = *(const bf16x8*)&As[(mh + i * 16 + l16) * 32 + quad * 8];
#pragma unroll
        for (int i = 0; i < 4; ++i)
            bq[i] = *(const bf16x8*)&Bs[(nh + i * 16 + l16) * 32 + quad * 8];
#pragma unroll
        for (int i = 0; i < 4; ++i)
#pragma unroll
            for (int j = 0; j < 4; ++j)
                acc[i][j] = mfma16(af[i], bq[j], acc[i][j]);
        __syncthreads();
    }

#pragma unroll
    for (int j = 0; j < 4; ++j) {
        const int col = n0 + nh + j * 16 + l16;
        const float bv = bias[col];
        if constexpr (OM == 2) {
            // V^T scatter: Vt[((b*16+h)*64+d)*2048 + skv]
            const int b_ = m0 >> 11;
            const long base = ((long)((b_ * 16 + (col >> 6)) * 64 + (col & 63))) << 11;
#pragma unroll
            for (int i = 0; i < 4; ++i)
#pragma unroll
                for (int r = 0; r < 4; ++r) {
                    int row = m0 + mh + i * 16 + quad * 4 + r;
                    ((bf16*)Yv)[base + (row & 2047)] = f2bf(acc[i][j][r] + bv);
                }
        } else {
#pragma unroll
            for (int i = 0; i < 4; ++i)
#pragma unroll
                for (int r = 0; r < 4; ++r) {
                    int row = m0 + mh + i * 16 + quad * 4 + r;
                    float v = acc[i][j][r] + bv;
                    if constexpr (OM == 1)
                        ((float*)Yv)[(long)row * Nd + col] = v;
                    else
                        ((bf16*)Yv)[(long)row * Nd + col] = f2bf(v);
                }
        }
    }
}

// ---------------------------------------------------------------------------
// StableMax cross-attention. One block per (b, h, 128-row q-tile).
// V comes pre-transposed (Vt layout [b,h,d,skv]) -> vectorized staging.
// stablemax via sign symmetry: u = 1 + |x|/8; s = x>=0 ? u : 1/u.
// ---------------------------------------------------------------------------
__global__ __launch_bounds__(256) void attn_kernel(
    const bf16* __restrict__ Q, const bf16* __restrict__ K,
    const bf16* __restrict__ Vt, bf16* __restrict__ C) {
    constexpr int E = 1024, S = 2048;
    __shared__ bf16 Ks[64 * 72];    // [kv][d]
    __shared__ bf16 VTs[64 * 72];   // [d][kv]
    __shared__ bf16 Ps[4][32 * 72]; // per-wave P tile [q_local][kv]

    const int tid = threadIdx.x;
    const int wid = tid >> 6, lane = tid & 63;
    const int l16 = lane & 15, quad = lane >> 4;
    const int qt = blockIdx.x, h = blockIdx.y, b = blockIdx.z;

    const long q0 = (long)b * S + qt * 128;
    const bf16* Qg = Q + q0 * E + h * 64;
    const bf16* Kg = K + (long)b * S * E + h * 64;
    const bf16* Vg = Vt + ((long)(b * 16 + h) << 17);  // [d][2048]

    bf16x8 qf[2][2];
#pragma unroll
    for (int mt = 0; mt < 2; ++mt)
#pragma unroll
        for (int kc = 0; kc < 2; ++kc)
            qf[mt][kc] = *(const bf16x8*)(Qg + (long)(wid * 32 + mt * 16 + l16) * E + kc * 32 + quad * 8);

    f32x4 ctx[2][4];
    f32x4 den[2];
#pragma unroll
    for (int mt = 0; mt < 2; ++mt) {
        den[mt] = (f32x4){0.f, 0.f, 0.f, 0.f};
#pragma unroll
        for (int nt = 0; nt < 4; ++nt) ctx[mt][nt] = (f32x4){0.f, 0.f, 0.f, 0.f};
    }

    const int krow = tid >> 2, kcol = (tid & 3) * 16;  // K and V^T staging coords

    for (int kv0 = 0; kv0 < S; kv0 += 64) {
        {   // K tile [64 kv][64 d], row-major
            const bf16* kp = Kg + (long)(kv0 + krow) * E + kcol;
            *(bf16x8*)&Ks[krow * 72 + kcol] = *(const bf16x8*)kp;
            *(bf16x8*)&Ks[krow * 72 + kcol + 8] = *(const bf16x8*)(kp + 8);
        }
        {   // V^T tile [64 d][64 kv] — straight copy from Vt
            const bf16* vp = Vg + (long)krow * S + kv0 + kcol;
            *(bf16x8*)&VTs[krow * 72 + kcol] = *(const bf16x8*)vp;
            *(bf16x8*)&VTs[krow * 72 + kcol + 8] = *(const bf16x8*)(vp + 8);
        }
        __syncthreads();

        bf16x8 kf[4][2];
#pragma unroll
        for (int nt = 0; nt < 4; ++nt)
#pragma unroll
            for (int kc = 0; kc < 2; ++kc)
                kf[nt][kc] = *(const bf16x8*)&Ks[(nt * 16 + l16) * 72 + kc * 32 + quad * 8];
        f32x4 sacc[2][4];
#pragma unroll
        for (int mt = 0; mt < 2; ++mt)
#pragma unroll
            for (int nt = 0; nt < 4; ++nt) sacc[mt][nt] = (f32x4){0.f, 0.f, 0.f, 0.f};
#pragma unroll
        for (int mt = 0; mt < 2; ++mt)
#pragma unroll
            for (int nt = 0; nt < 4; ++nt)
#pragma unroll
                for (int kc = 0; kc < 2; ++kc)
                    sacc[mt][nt] = mfma16(qf[mt][kc], kf[nt][kc], sacc[mt][nt]);

        // stablemax: u = 1 + |x|/8 ; s = x>=0 ? u : 1/u
#pragma unroll
        for (int mt = 0; mt < 2; ++mt) {
#pragma unroll
            for (int nt = 0; nt < 4; ++nt) {
                f32x4 s;
#pragma unroll
                for (int r = 0; r < 4; ++r) {
                    float x = sacc[mt][nt][r];
                    float u = __builtin_fmaf(__builtin_fabsf(x), 0.125f, 1.0f);
                    float sv = (x >= 0.f) ? u : __builtin_amdgcn_rcpf(u);
                    s[r] = sv;
                    Ps[wid][(mt * 16 + quad * 4 + r) * 72 + nt * 16 + l16] = f2bf(sv);
                }
                den[mt] += s;
            }
        }

        // PV: ctx += P @ V
        bf16x8 pf[2][2], vf[4][2];
#pragma unroll
        for (int mt = 0; mt < 2; ++mt)
#pragma unroll
            for (int kc = 0; kc < 2; ++kc)
                pf[mt][kc] = *(const bf16x8*)&Ps[wid][(mt * 16 + l16) * 72 + kc * 32 + quad * 8];
#pragma unroll
        for (int nt = 0; nt < 4; ++nt)
#pragma unroll
            for (int kc = 0; kc < 2; ++kc)
                vf[nt][kc] = *(const bf16x8*)&VTs[(nt * 16 + l16) * 72 + kc * 32 + quad * 8];
#pragma unroll
        for (int mt = 0; mt < 2; ++mt)
#pragma unroll
            for (int nt = 0; nt < 4; ++nt)
#pragma unroll
                for (int kc = 0; kc < 2; ++kc)
                    ctx[mt][nt] = mfma16(pf[mt][kc], vf[nt][kc], ctx[mt][nt]);
        __syncthreads();
    }

#pragma unroll
    for (int mt = 0; mt < 2; ++mt) {
#pragma unroll
        for (int r = 0; r < 4; ++r) {
            float d = den[mt][r];
            d += __shfl_xor(d, 1, 16);
            d += __shfl_xor(d, 2, 16);
            d += __shfl_xor(d, 4, 16);
            d += __shfl_xor(d, 8, 16);
            den[mt][r] = d;
        }
    }

#pragma unroll
    for (int mt = 0; mt < 2; ++mt) {
#pragma unroll
        for (int nt = 0; nt < 4; ++nt) {
#pragma unroll
            for (int r = 0; r < 4; ++r) {
                int row = wid * 32 + mt * 16 + quad * 4 + r;
                float v = ctx[mt][nt][r] * __builtin_amdgcn_rcpf(den[mt][r]);
                C[(q0 + row) * E + h * 64 + nt * 16 + l16] = f2bf(v);
            }
        }
    }
}

// ---------------------------------------------------------------------------
extern "C" void kernel_launch(void* const* d_in, const int* in_sizes, int n_in,
                              void* d_out, int out_size, void* d_ws, size_t ws_size,
                              hipStream_t stream) {
    const float* query = (const float*)d_in[0];
    const float* keyv  = (const float*)d_in[1];
    const float* Wq = (const float*)d_in[2];
    const float* bq = (const float*)d_in[3];
    const float* Wk = (const float*)d_in[4];
    const float* bk = (const float*)d_in[5];
    const float* Wv = (const float*)d_in[6];
    const float* bv = (const float*)d_in[7];
    const float* Wo = (const float*)d_in[8];
    const float* bo = (const float*)d_in[9];

    char* ws = (char*)d_ws;
    bf16* Wb  = (bf16*)ws;                  // 8 MB: Wq,Wk,Wv,Wo bf16
    bf16* KVa = (bf16*)(ws + (8l << 20));   // 16 MB key_value bf16 (reused as Cw)
    bf16* Qw  = (bf16*)(ws + (24l << 20));  // 16 MB
    bf16* Kw  = (bf16*)(ws + (40l << 20));  // 16 MB
    bf16* Vt  = (bf16*)(ws + (56l << 20));  // 16 MB V^T [b,h,d,skv]  (total 72 MB)
    bf16* Cw  = KVa;                        // alias: KVa dead after V-GEMM

    cast_inputs<<<12288, 256, 0, stream>>>(Wq, Wk, Wv, Wo, keyv, Wb, KVa);

    dim3 gg(8, 64);  // N/128, M/128
    gemm_bt<float, 0><<<gg, 256, 0, stream>>>(query, Wb, bq, Qw);
    gemm_bt<bf16, 0><<<gg, 256, 0, stream>>>(KVa, Wb + (1l << 20), bk, Kw);
    gemm_bt<bf16, 2><<<gg, 256, 0, stream>>>(KVa, Wb + (2l << 20), bv, Vt);

    attn_kernel<<<dim3(16, 16, 4), 256, 0, stream>>>(Qw, Kw, Vt, Cw);

    gemm_bt<bf16, 1><<<gg, 256, 0, stream>>>(Cw, Wb + (3l << 20), bo, (float*)d_out);
}

// Round 3
// 381.836 us; speedup vs baseline: 1.2250x; 1.0220x over previous
//
#include <hip/hip_runtime.h>

typedef __bf16 bf16;
typedef __bf16 bf16x8 __attribute__((ext_vector_type(8)));
typedef __bf16 bf16x4 __attribute__((ext_vector_type(4)));
typedef __bf16 bf16x2 __attribute__((ext_vector_type(2)));
typedef float f32x4 __attribute__((ext_vector_type(4)));

__device__ __forceinline__ f32x4 mfma16(bf16x8 a, bf16x8 b, f32x4 c) {
    return __builtin_amdgcn_mfma_f32_16x16x32_bf16(a, b, c, 0, 0, 0);
}

// async global -> LDS, 16 bytes per lane (dest = wave-uniform base + lane*16)
#define GLOAD_LDS16(gp, lp)                                                    \
    __builtin_amdgcn_global_load_lds(                                          \
        (const __attribute__((address_space(1))) unsigned int*)(gp),           \
        (__attribute__((address_space(3))) unsigned int*)(lp), 16, 0, 0)

// ---------------------------------------------------------------------------
// Cast the four 1024x1024 fp32 weights + key_value (8M floats) to bf16.
// ---------------------------------------------------------------------------
__global__ __launch_bounds__(256) void cast_inputs(
    const float* __restrict__ w0, const float* __restrict__ w1,
    const float* __restrict__ w2, const float* __restrict__ w3,
    const float* __restrict__ kv, bf16* __restrict__ Wb,
    bf16* __restrict__ KVa) {
    long i4 = (long)blockIdx.x * 256 + threadIdx.x;  // float4 index
    const float* src;
    bf16* dst;
    long loc;
    if (i4 < 1048576) {  // 4 weights x 262144 float4
        int which = (int)(i4 >> 18);
        loc = (i4 & 262143) << 2;
        src = which == 0 ? w0 : which == 1 ? w1 : which == 2 ? w2 : w3;
        dst = Wb + ((long)which << 20);
    } else {             // key_value: 2097152 float4
        loc = (i4 - 1048576) << 2;
        src = kv;
        dst = KVa;
    }
    float4 f = *(const float4*)(src + loc);
    bf16x4 o;
    o[0] = (bf16)f.x; o[1] = (bf16)f.y; o[2] = (bf16)f.z; o[3] = (bf16)f.w;
    *(bf16x4*)(dst + loc) = o;
}

// ---------------------------------------------------------------------------
// C[M,N] = A[M,K] @ W[N,K]^T + bias. M=8192, N=K=1024.
// 128x128 tile, BK=32, 4 waves each 64x64 (m97 pattern).
// AT: float (convert during staging, native cvt_pk) or bf16 (global_load_lds).
// OM: 0 = bf16 row-major, 1 = f32 row-major, 2 = bf16 V^T [b,h,d,skv] via
//     LDS transpose epilogue (coalesced 256B stores).
// ---------------------------------------------------------------------------
template <typename AT, int OM>
__global__ __launch_bounds__(256) void gemm_bt(
    const AT* __restrict__ A, const bf16* __restrict__ Wt,
    const float* __restrict__ bias, void* __restrict__ Yv) {
    constexpr int Kd = 1024, Nd = 1024;
    constexpr int TP = 132;  // transpose-epilogue row stride (pad 4)
    __shared__ bf16 smem[OM == 2 ? 128 * TP : 8192];
    bf16* As = smem;
    bf16* Bs = smem + 4096;
    const int tid = threadIdx.x;
    const int wid = tid >> 6, lane = tid & 63;
    const int l16 = lane & 15, quad = lane >> 4;
    const int n0 = blockIdx.x * 128, m0 = blockIdx.y * 128;
    const int mh = (wid >> 1) * 64, nh = (wid & 1) * 64;

    f32x4 acc[4][4];
#pragma unroll
    for (int i = 0; i < 4; ++i)
#pragma unroll
        for (int j = 0; j < 4; ++j) acc[i][j] = (f32x4){0.f, 0.f, 0.f, 0.f};

    const int c0 = tid, c1 = tid + 256;       // 16B chunk ids for async staging
    const int sr = tid >> 1, sc = (tid & 1) * 16;  // fp32-A staging coords

    for (int k0 = 0; k0 < Kd; k0 += 32) {
        GLOAD_LDS16(Wt + (long)(n0 + (c0 >> 2)) * Kd + k0 + (c0 & 3) * 8, &Bs[c0 * 8]);
        GLOAD_LDS16(Wt + (long)(n0 + (c1 >> 2)) * Kd + k0 + (c1 & 3) * 8, &Bs[(long)c1 * 8]);
        if constexpr (sizeof(AT) == 4) {
            const float* ap = (const float*)A + (long)(m0 + sr) * Kd + k0 + sc;
            float4 f0 = *(const float4*)(ap + 0);
            float4 f1 = *(const float4*)(ap + 4);
            float4 f2 = *(const float4*)(ap + 8);
            float4 f3 = *(const float4*)(ap + 12);
            bf16x8 p0, p1;
            p0[0] = (bf16)f0.x; p0[1] = (bf16)f0.y; p0[2] = (bf16)f0.z; p0[3] = (bf16)f0.w;
            p0[4] = (bf16)f1.x; p0[5] = (bf16)f1.y; p0[6] = (bf16)f1.z; p0[7] = (bf16)f1.w;
            p1[0] = (bf16)f2.x; p1[1] = (bf16)f2.y; p1[2] = (bf16)f2.z; p1[3] = (bf16)f2.w;
            p1[4] = (bf16)f3.x; p1[5] = (bf16)f3.y; p1[6] = (bf16)f3.z; p1[7] = (bf16)f3.w;
            *(bf16x8*)&As[sr * 32 + sc] = p0;
            *(bf16x8*)&As[sr * 32 + sc + 8] = p1;
        } else {
            GLOAD_LDS16((const bf16*)A + (long)(m0 + (c0 >> 2)) * Kd + k0 + (c0 & 3) * 8, &As[c0 * 8]);
            GLOAD_LDS16((const bf16*)A + (long)(m0 + (c1 >> 2)) * Kd + k0 + (c1 & 3) * 8, &As[(long)c1 * 8]);
        }
        __syncthreads();
        bf16x8 af[4], bq[4];
#pragma unroll
        for (int i = 0; i < 4; ++i)
            af[i] = *(const bf16x8*)&As[(mh + i * 16 + l16) * 32 + quad * 8];
#pragma unroll
        for (int i = 0; i < 4; ++i)
            bq[i] = *(const bf16x8*)&Bs[(nh + i * 16 + l16) * 32 + quad * 8];
#pragma unroll
        for (int i = 0; i < 4; ++i)
#pragma unroll
            for (int j = 0; j < 4; ++j)
                acc[i][j] = mfma16(af[i], bq[j], acc[i][j]);
        __syncthreads();
    }

    if constexpr (OM == 2) {
        // stage transposed tile Ts[col][row] with packed row-pair b32 writes
        // (last K-iter barrier already drained all LDS reads)
#pragma unroll
        for (int j = 0; j < 4; ++j) {
            const int col = nh + j * 16 + l16;
            const float bv = bias[n0 + col];
#pragma unroll
            for (int i = 0; i < 4; ++i)
#pragma unroll
                for (int p = 0; p < 2; ++p) {
                    bf16x2 pk2;
                    pk2[0] = (bf16)(acc[i][j][p * 2 + 0] + bv);
                    pk2[1] = (bf16)(acc[i][j][p * 2 + 1] + bv);
                    *(bf16x2*)&smem[col * TP + mh + i * 16 + quad * 4 + p * 2] = pk2;
                }
        }
        __syncthreads();
        // coalesced stores: Vt[((b*16+h)*64+d)*2048 + skv]
        const int b_ = m0 >> 11, skv0 = m0 & 2047;
        const int rowc = tid & 15;
#pragma unroll
        for (int c = 0; c < 8; ++c) {
            const int col = (tid >> 4) + c * 16;
            const int colg = n0 + col;
            bf16x8 v = *(const bf16x8*)&smem[col * TP + rowc * 8];
            const long base = ((long)((b_ * 16 + (colg >> 6)) * 64 + (colg & 63))) << 11;
            *(bf16x8*)((bf16*)Yv + base + skv0 + rowc * 8) = v;
        }
    } else {
#pragma unroll
        for (int j = 0; j < 4; ++j) {
            const int col = n0 + nh + j * 16 + l16;
            const float bv = bias[col];
#pragma unroll
            for (int i = 0; i < 4; ++i)
#pragma unroll
                for (int r = 0; r < 4; ++r) {
                    int row = m0 + mh + i * 16 + quad * 4 + r;
                    float v = acc[i][j][r] + bv;
                    if constexpr (OM == 1)
                        ((float*)Yv)[(long)row * Nd + col] = v;
                    else
                        ((bf16*)Yv)[(long)row * Nd + col] = (bf16)v;
                }
        }
    }
}

// ---------------------------------------------------------------------------
// StableMax cross-attention. One block per (b, h, 128-row q-tile).
// V pre-transposed (Vt layout [b,h,d,skv]). stablemax via sign symmetry:
// u = 1 + |x|/8; s = x>=0 ? u : 1/u. Native bf16 cvt on the P path.
// ---------------------------------------------------------------------------
__global__ __launch_bounds__(256) void attn_kernel(
    const bf16* __restrict__ Q, const bf16* __restrict__ K,
    const bf16* __restrict__ Vt, bf16* __restrict__ C) {
    constexpr int E = 1024, S = 2048;
    __shared__ bf16 Ks[64 * 72];    // [kv][d]
    __shared__ bf16 VTs[64 * 72];   // [d][kv]
    __shared__ bf16 Ps[4][32 * 72]; // per-wave P tile [q_local][kv]

    const int tid = threadIdx.x;
    const int wid = tid >> 6, lane = tid & 63;
    const int l16 = lane & 15, quad = lane >> 4;
    const int qt = blockIdx.x, h = blockIdx.y, b = blockIdx.z;

    const long q0 = (long)b * S + qt * 128;
    const bf16* Qg = Q + q0 * E + h * 64;
    const bf16* Kg = K + (long)b * S * E + h * 64;
    const bf16* Vg = Vt + ((long)(b * 16 + h) << 17);  // [d][2048]

    bf16x8 qf[2][2];
#pragma unroll
    for (int mt = 0; mt < 2; ++mt)
#pragma unroll
        for (int kc = 0; kc < 2; ++kc)
            qf[mt][kc] = *(const bf16x8*)(Qg + (long)(wid * 32 + mt * 16 + l16) * E + kc * 32 + quad * 8);

    f32x4 ctx[2][4];
    f32x4 den[2];
#pragma unroll
    for (int mt = 0; mt < 2; ++mt) {
        den[mt] = (f32x4){0.f, 0.f, 0.f, 0.f};
#pragma unroll
        for (int nt = 0; nt < 4; ++nt) ctx[mt][nt] = (f32x4){0.f, 0.f, 0.f, 0.f};
    }

    const int krow = tid >> 2, kcol = (tid & 3) * 16;

    for (int kv0 = 0; kv0 < S; kv0 += 64) {
        {   // K tile [64 kv][64 d]
            const bf16* kp = Kg + (long)(kv0 + krow) * E + kcol;
            *(bf16x8*)&Ks[krow * 72 + kcol] = *(const bf16x8*)kp;
            *(bf16x8*)&Ks[krow * 72 + kcol + 8] = *(const bf16x8*)(kp + 8);
        }
        {   // V^T tile [64 d][64 kv] — straight copy
            const bf16* vp = Vg + (long)krow * S + kv0 + kcol;
            *(bf16x8*)&VTs[krow * 72 + kcol] = *(const bf16x8*)vp;
            *(bf16x8*)&VTs[krow * 72 + kcol + 8] = *(const bf16x8*)(vp + 8);
        }
        __syncthreads();

        bf16x8 kf[4][2];
#pragma unroll
        for (int nt = 0; nt < 4; ++nt)
#pragma unroll
            for (int kc = 0; kc < 2; ++kc)
                kf[nt][kc] = *(const bf16x8*)&Ks[(nt * 16 + l16) * 72 + kc * 32 + quad * 8];
        f32x4 sacc[2][4];
#pragma unroll
        for (int mt = 0; mt < 2; ++mt)
#pragma unroll
            for (int nt = 0; nt < 4; ++nt) sacc[mt][nt] = (f32x4){0.f, 0.f, 0.f, 0.f};
#pragma unroll
        for (int mt = 0; mt < 2; ++mt)
#pragma unroll
            for (int nt = 0; nt < 4; ++nt)
#pragma unroll
                for (int kc = 0; kc < 2; ++kc)
                    sacc[mt][nt] = mfma16(qf[mt][kc], kf[nt][kc], sacc[mt][nt]);

        // stablemax: u = 1 + |x|/8 ; s = x>=0 ? u : 1/u
#pragma unroll
        for (int mt = 0; mt < 2; ++mt) {
#pragma unroll
            for (int nt = 0; nt < 4; ++nt) {
                f32x4 s;
#pragma unroll
                for (int r = 0; r < 4; ++r) {
                    float x = sacc[mt][nt][r];
                    float u = __builtin_fmaf(__builtin_fabsf(x), 0.125f, 1.0f);
                    float sv = (x >= 0.f) ? u : __builtin_amdgcn_rcpf(u);
                    s[r] = sv;
                    Ps[wid][(mt * 16 + quad * 4 + r) * 72 + nt * 16 + l16] = (bf16)sv;
                }
                den[mt] += s;
            }
        }

        // PV: ctx += P @ V
        bf16x8 pf[2][2], vf[4][2];
#pragma unroll
        for (int mt = 0; mt < 2; ++mt)
#pragma unroll
            for (int kc = 0; kc < 2; ++kc)
                pf[mt][kc] = *(const bf16x8*)&Ps[wid][(mt * 16 + l16) * 72 + kc * 32 + quad * 8];
#pragma unroll
        for (int nt = 0; nt < 4; ++nt)
#pragma unroll
            for (int kc = 0; kc < 2; ++kc)
                vf[nt][kc] = *(const bf16x8*)&VTs[(nt * 16 + l16) * 72 + kc * 32 + quad * 8];
#pragma unroll
        for (int mt = 0; mt < 2; ++mt)
#pragma unroll
            for (int nt = 0; nt < 4; ++nt)
#pragma unroll
                for (int kc = 0; kc < 2; ++kc)
                    ctx[mt][nt] = mfma16(pf[mt][kc], vf[nt][kc], ctx[mt][nt]);
        __syncthreads();
    }

#pragma unroll
    for (int mt = 0; mt < 2; ++mt) {
#pragma unroll
        for (int r = 0; r < 4; ++r) {
            float d = den[mt][r];
            d += __shfl_xor(d, 1, 16);
            d += __shfl_xor(d, 2, 16);
            d += __shfl_xor(d, 4, 16);
            d += __shfl_xor(d, 8, 16);
            den[mt][r] = d;
        }
    }

#pragma unroll
    for (int mt = 0; mt < 2; ++mt) {
#pragma unroll
        for (int nt = 0; nt < 4; ++nt) {
#pragma unroll
            for (int r = 0; r < 4; ++r) {
                int row = wid * 32 + mt * 16 + quad * 4 + r;
                float v = ctx[mt][nt][r] * __builtin_amdgcn_rcpf(den[mt][r]);
                C[(q0 + row) * E + h * 64 + nt * 16 + l16] = (bf16)v;
            }
        }
    }
}

// ---------------------------------------------------------------------------
extern "C" void kernel_launch(void* const* d_in, const int* in_sizes, int n_in,
                              void* d_out, int out_size, void* d_ws, size_t ws_size,
                              hipStream_t stream) {
    const float* query = (const float*)d_in[0];
    const float* keyv  = (const float*)d_in[1];
    const float* Wq = (const float*)d_in[2];
    const float* bq = (const float*)d_in[3];
    const float* Wk = (const float*)d_in[4];
    const float* bk = (const float*)d_in[5];
    const float* Wv = (const float*)d_in[6];
    const float* bv = (const float*)d_in[7];
    const float* Wo = (const float*)d_in[8];
    const float* bo = (const float*)d_in[9];

    char* ws = (char*)d_ws;
    bf16* Wb  = (bf16*)ws;                  // 8 MB: Wq,Wk,Wv,Wo bf16
    bf16* KVa = (bf16*)(ws + (8l << 20));   // 16 MB key_value bf16 (reused as Cw)
    bf16* Qw  = (bf16*)(ws + (24l << 20));  // 16 MB
    bf16* Kw  = (bf16*)(ws + (40l << 20));  // 16 MB
    bf16* Vt  = (bf16*)(ws + (56l << 20));  // 16 MB V^T [b,h,d,skv]  (total 72 MB)
    bf16* Cw  = KVa;                        // alias: KVa dead after V-GEMM

    cast_inputs<<<12288, 256, 0, stream>>>(Wq, Wk, Wv, Wo, keyv, Wb, KVa);

    dim3 gg(8, 64);  // N/128, M/128
    gemm_bt<float, 0><<<gg, 256, 0, stream>>>(query, Wb, bq, Qw);
    gemm_bt<bf16, 0><<<gg, 256, 0, stream>>>(KVa, Wb + (1l << 20), bk, Kw);
    gemm_bt<bf16, 2><<<gg, 256, 0, stream>>>(KVa, Wb + (2l << 20), bv, Vt);

    attn_kernel<<<dim3(16, 16, 4), 256, 0, stream>>>(Qw, Kw, Vt, Cw);

    gemm_bt<bf16, 1><<<gg, 256, 0, stream>>>(Cw, Wb + (3l << 20), bo, (float*)d_out);
}